// Round 6
// baseline (213.065 us; speedup 1.0000x reference)
//
#include <hip/hip_runtime.h>
#include <hip/hip_fp16.h>
#include <cfloat>
#include <cmath>

#define N_NODES 20000
#define MAXD 32
#define F 128

// fused tiling: one block = 16 nodes (stage1) + its own 16x128 GEMM tile.
// 20000 = 1250 * 16 exactly -> no remainder, no guards, no cross-block deps.
#define MTILE 16
#define NBLK (N_NODES / MTILE)  // 1250 blocks

typedef _Float16 half8 __attribute__((ext_vector_type(8)));
typedef float f32x4 __attribute__((ext_vector_type(4)));
typedef unsigned int u32x4 __attribute__((ext_vector_type(4)));
typedef unsigned short us8v __attribute__((ext_vector_type(8)));

// ---------------- stage-1 core: trimmed-mean aggregation ---------------------
// CRITICAL invariants (measured):
//  * node index must be wave-uniform scalar — per-lane i => ~10x VALU blowup.
//  * private arrays pow2-sized, static indices (else LDS-promote + spill).
//  * one node per 128-thread group; exact-n templates: compile-time b,
//    direct-register rank extraction, pad-pruned sort network.
//  * R3 lesson: NO cross-block spin/fence protocols (container hang).
//  * R5 lesson: gather is LATENCY-bound, not BW-bound (fp16 gather halved
//    FETCH 61.7->30.4 MB yet ran +5us slower, absmax 4.5x worse). Reverted.
//  * R6: cross-node software pipelining — node it+1's 32 gathers issue into a
//    second register buffer while node it's ~1000-cycle sort runs; one static
//    rotate per iteration keeps ONE switch copy (I$).

template <int SZ, int NV>
__device__ __forceinline__ void oe_sort_n(float (&a)[SZ]) {
#pragma unroll
  for (int p = 1; p < SZ; p <<= 1) {
#pragma unroll
    for (int q = p; q >= 1; q >>= 1) {
#pragma unroll
      for (int j = q % p; j <= SZ - 1 - q; j += 2 * q) {
#pragma unroll
        for (int i = 0; i < q; ++i) {
          int x = i + j, y = i + j + q;
          if (y < NV && (x / (2 * p)) == (y / (2 * p))) {  // y<NV ⊆ y<SZ
            float mn = fminf(a[x], a[y]);
            float mx = fmaxf(a[x], a[y]);
            a[x] = mn;
            a[y] = mx;
          }
        }
      }
    }
  }
}

// b = max(min(n/2 - (1-n%2), (int)floor_f32(n*0.45f)), 1) — f32 mult matches
// jnp exactly (e.g. n=20: 20*0.449999988f = 8.9999998 -> 8, not 9).
template <int N>
struct TrimB {
  static constexpr int b_raw = N / 2 - (1 - (N & 1));
  static constexpr int b_cap = (int)((float)N * 0.45f);  // trunc == floor (pos)
  static constexpr int b_min = b_raw < b_cap ? b_raw : b_cap;
  static constexpr int value = b_min > 1 ? b_min : 1;
};

// Exact trimmed sum over PRE-GATHERED neighbor values (ko/nrm filled by the
// pipelined loader; only d<N entries valid). Stable-rank semantics match
// jnp.argsort ties-by-slot. Fast path: no equal-key run straddles either trim
// boundary -> pure value test. Slow path (rare): exact stable-rank scan.
template <int SZ, int N>
__device__ __forceinline__ float trimmed_sum_pre(const float (&ko)[32],
                                                 const float (&nrm)[32]) {
  constexpr int B = TrimB<N>::value;
  constexpr int NB = N - B;

  float k[SZ];
#pragma unroll
  for (int d = 0; d < N; ++d) k[d] = ko[d];
#pragma unroll
  for (int d = N; d < SZ; ++d) k[d] = FLT_MAX;  // pads sort past all valid keys

  oe_sort_n<SZ, N>(k);

  const float lo  = k[B];       // compile-time positions -> direct reg reads
  const float hi  = k[NB - 1];
  const float lom = k[B - 1];
  const float him = k[NB];

  float sum = 0.f;
  if ((lom < lo) & (hi < him)) {
#pragma unroll
    for (int d = 0; d < N; ++d) {
      bool keep = (ko[d] >= lo) & (ko[d] <= hi);
      sum = fmaf(keep ? ko[d] : 0.f, nrm[d], sum);
    }
  } else {
    int c_lt_lo = 0, c_lt_hi = 0;
#pragma unroll
    for (int d = 0; d < N; ++d) {
      c_lt_lo += (ko[d] < lo) ? 1 : 0;
      c_lt_hi += (ko[d] < hi) ? 1 : 0;
    }
    int run_lo = 0, run_hi = 0;
#pragma unroll
    for (int d = 0; d < N; ++d) {
      const float kd = ko[d];
      const float m = kd * nrm[d];
      const bool eql = (kd == lo);
      const bool eqh = (kd == hi);
      const bool lh = (lo < hi);
      const bool btw = (kd > lo) & (kd < hi);
      const int r_lo = c_lt_lo + run_lo;  // stable rank if kd==lo
      const int r_hi = c_lt_hi + run_hi;  // stable rank if kd==hi
      const bool inc = btw
                     | (eql & (r_lo >= B) & (lh | (r_lo < NB)))
                     | (lh & eqh & (r_hi < NB));
      sum += inc ? m : 0.f;
      run_lo += eql ? 1 : 0;
      run_hi += eqh ? 1 : 0;
    }
  }
  return sum;
}

// a = hi + lo captures ~22 mantissa bits; packed into one u32 (hi low16).
__device__ __forceinline__ unsigned int split_pack(float v) {
  _Float16 hi = (_Float16)v;            // rne f32->f16
  _Float16 lo = (_Float16)(v - (float)hi);
  unsigned short hb = __builtin_bit_cast(unsigned short, hi);
  unsigned short lb = __builtin_bit_cast(unsigned short, lo);
  return (unsigned int)hb | ((unsigned int)lb << 16);
}

// ---------------- W pre-split: fp32 [k][n] -> fp16 hi/lo transposed [n][k] ---
__global__ __launch_bounds__(256) void whl_prep(const float* __restrict__ W,
                                                _Float16* __restrict__ Whl) {
  const int e = blockIdx.x * 256 + threadIdx.x;  // e = n*128 + k
  const int n = e >> 7, k = e & 127;
  const float w = W[k * F + n];
  const _Float16 hi = (_Float16)w;
  Whl[e] = hi;
  Whl[16384 + e] = (_Float16)(w - (float)hi);
}

// ---------------- fused kernel: pipelined 16-node aggregation + GEMM tile ----
// Phase 1: 8 iterations x 2 nodes (each 128-thread half = one node; i is SGPR).
// Pipelined: iteration it issues node it+1's gathers (koB, wave-uniform-
// predicated static unroll — n runtime but uniform, indices static -> regs),
// then runs node it's sort/sum from koA (loads already landed), then rotates
// B->A (32 v_mov + 32 s_mov ≈ 100cyc, ~10% of one sort). nrm/self/deg loads
// are consumed post-sort -> lgkmcnt naturally hides them; only the ko gather
// chain needed explicit prefetch.
// Phase 2 (after ONE barrier): 16x128 fp16x2-split MFMA tile (refcheck-
// verified operand/D layouts), B from global Whl (64KB, L2-hot).
__global__ __launch_bounds__(256) void gcn_fused(
    const float* __restrict__ h, const float* __restrict__ norm,
    const int* __restrict__ nbr, const int* __restrict__ deg,
    const _Float16* __restrict__ Whl, const float* __restrict__ bias,
    float* __restrict__ out) {
  __shared__ unsigned int As[MTILE * F];  // 8 KB, swizzled split-packed rows
  const int tid = threadIdx.x;
  const int hw = __builtin_amdgcn_readfirstlane(tid) >> 7;  // 0/1, SGPR
  const int f = tid & 127;
  const int base = blockIdx.x * MTILE;

  float koA[32], nrmA[32];
  float koB[32], nrmB[32];

  // prologue: gather node (0,hw)'s neighbors into A
  int n_cur;
  {
    const int i = base + hw;
    n_cur = deg[i];
    const int ne = (n_cur <= 3) ? 0 : n_cur;
    const int* nr = nbr + i * MAXD;
#pragma unroll
    for (int d = 0; d < 32; ++d) {
      if (d < ne) {                 // wave-uniform branch (ne is SGPR)
        const int src = nr[d];      // scalar load
        nrmA[d] = norm[src];        // scalar load
        koA[d] = h[src * F + f];    // vector load, coalesced 256B/wave
      }
    }
  }

#pragma unroll 1  // ONE copy of the switch (I$); pipeline via A/B rotate
  for (int it = 0; it < 8; ++it) {
    // ---- prefetch node it+1 into B (issues before the sort below) ----
    int n_next = 0;
    if (it < 7) {
      const int i_next = base + (it + 1) * 2 + hw;
      n_next = deg[i_next];
      const int ne = (n_next <= 3) ? 0 : n_next;
      const int* nr = nbr + i_next * MAXD;
#pragma unroll
      for (int d = 0; d < 32; ++d) {
        if (d < ne) {
          const int src = nr[d];
          nrmB[d] = norm[src];
          koB[d] = h[src * F + f];
        }
      }
    }

    // ---- process node it from A (gathers landed during previous sort) ----
    const int nl = it * 2 + hw;
    const int i = base + nl;
    const float ni = norm[i];
    const float hif = h[i * F + f];

    float val;
    if (n_cur <= 3) {  // N_NEIGH_THRESHOLD branch (exact)
      val = (float)n_cur * hif * ni * ni;
    } else {
      float ts;
      int b;
      switch (n_cur) {
#define TS_CASE(NN, SS) \
        case NN: ts = trimmed_sum_pre<SS, NN>(koA, nrmA); b = TrimB<NN>::value; break;
        TS_CASE(4, 4)
        TS_CASE(5, 8) TS_CASE(6, 8) TS_CASE(7, 8) TS_CASE(8, 8)
        TS_CASE(9, 16) TS_CASE(10, 16) TS_CASE(11, 16) TS_CASE(12, 16)
        TS_CASE(13, 16) TS_CASE(14, 16) TS_CASE(15, 16) TS_CASE(16, 16)
        TS_CASE(17, 32) TS_CASE(18, 32) TS_CASE(19, 32) TS_CASE(20, 32)
        TS_CASE(21, 32) TS_CASE(22, 32) TS_CASE(23, 32) TS_CASE(24, 32)
        TS_CASE(25, 32) TS_CASE(26, 32) TS_CASE(27, 32) TS_CASE(28, 32)
        TS_CASE(29, 32) TS_CASE(30, 32) TS_CASE(31, 32)
        default: ts = trimmed_sum_pre<32, 32>(koA, nrmA); b = TrimB<32>::value; break;
#undef TS_CASE
      }
      val = (ts + hif * ni * (float)(2 * b)) * ni;
    }
    // swizzled LDS write: conflict-free (XOR const per node-row)
    As[nl * F + (f ^ ((nl & 7) << 2))] = split_pack(val);

    // ---- rotate B -> A (static copies; waits on B's loads AFTER the sort) --
    n_cur = n_next;
#pragma unroll
    for (int d = 0; d < 32; ++d) {
      koA[d] = koB[d];
      nrmA[d] = nrmB[d];
    }
  }

  __syncthreads();  // the only barrier: LDS tile complete

  // ---------------- phase 2: 16x128 fp16x2-split MFMA tile ------------------
  const int lane = tid & 63;
  const int wv = tid >> 6;      // wave -> cols [wv*32, wv*32+32)
  const int l16 = lane & 15;    // A row / B col within fragment
  const int kg = lane >> 4;     // k-group 0..3 (8 k each)
  const int row0 = base;
  const int colb = wv * 32;
  const int s = (l16 & 7) << 2; // read-side un-swizzle for row=l16

  f32x4 acc[2];
  acc[0] = (f32x4){0.f, 0.f, 0.f, 0.f};
  acc[1] = (f32x4){0.f, 0.f, 0.f, 0.f};

#pragma unroll
  for (int kc = 0; kc < F; kc += 32) {
    const int k0 = kc + kg * 8;
    // A fragment: rows l16, k = k0..k0+7. Two b128 reads; swizzle maps each
    // 4-aligned group bijectively, retrieving f = k0..k0+7 in order.
    u32x4 p0 = *(const u32x4*)(As + l16 * F + ((k0 + 0) ^ s));
    u32x4 p1 = *(const u32x4*)(As + l16 * F + ((k0 + 4) ^ s));
    us8v s0 = __builtin_bit_cast(us8v, p0);  // {h0,l0,h1,l1,...}
    us8v s1 = __builtin_bit_cast(us8v, p1);
    half8 ah = __builtin_bit_cast(half8,
        (us8v)__builtin_shufflevector(s0, s1, 0, 2, 4, 6, 8, 10, 12, 14));
    half8 al = __builtin_bit_cast(half8,
        (us8v)__builtin_shufflevector(s0, s1, 1, 3, 5, 7, 9, 11, 13, 15));
#pragma unroll
    for (int cf = 0; cf < 2; ++cf) {
      const int n = colb + cf * 16 + l16;
      half8 bh = *(const half8*)(Whl + n * F + k0);
      half8 bl = *(const half8*)(Whl + 16384 + n * F + k0);
      acc[cf] = __builtin_amdgcn_mfma_f32_16x16x32_f16(ah, bh, acc[cf], 0, 0, 0);
      acc[cf] = __builtin_amdgcn_mfma_f32_16x16x32_f16(ah, bl, acc[cf], 0, 0, 0);
      acc[cf] = __builtin_amdgcn_mfma_f32_16x16x32_f16(al, bh, acc[cf], 0, 0, 0);
    }
  }

  // bias + relu. D mapping: col = l16 (+cf*16+colb), row = kg*4 + r
  // (verified C/D layout, m89 + R1/R2/R4 refcheck).
#pragma unroll
  for (int cf = 0; cf < 2; ++cf) {
    const int col = colb + cf * 16 + l16;
    const float bv = bias[col];
#pragma unroll
    for (int r = 0; r < 4; ++r) {
      const int row = row0 + kg * 4 + r;
      out[(size_t)row * F + col] = fmaxf(acc[cf][r] + bv, 0.f);
    }
  }
}

extern "C" void kernel_launch(void* const* d_in, const int* in_sizes, int n_in,
                              void* d_out, int out_size, void* d_ws, size_t ws_size,
                              hipStream_t stream) {
  const float* h = (const float*)d_in[0];
  const float* norm = (const float*)d_in[1];
  const float* weight = (const float*)d_in[2];
  const float* bias = (const float*)d_in[3];
  const int* nbr = (const int*)d_in[4];
  const int* deg = (const int*)d_in[5];
  float* out = (float*)d_out;

  _Float16* Whl = (_Float16*)d_ws;  // 64 KB: split W^T hi|lo

  whl_prep<<<64, 256, 0, stream>>>(weight, Whl);
  gcn_fused<<<NBLK, 256, 0, stream>>>(h, norm, nbr, deg, Whl, bias, out);
}

// Round 7
// 122.504 us; speedup vs baseline: 1.7393x; 1.7393x over previous
//
#include <hip/hip_runtime.h>
#include <hip/hip_fp16.h>
#include <cfloat>
#include <cmath>

#define N_NODES 20000
#define MAXD 32
#define F 128

// fused tiling: one block = 16 nodes (stage1) + its own 16x128 GEMM tile.
// 20000 = 1250 * 16 exactly -> no remainder, no guards, no cross-block deps.
#define MTILE 16
#define NBLK (N_NODES / MTILE)  // 1250 blocks

typedef _Float16 half8 __attribute__((ext_vector_type(8)));
typedef float f32x4 __attribute__((ext_vector_type(4)));
typedef unsigned int u32x4 __attribute__((ext_vector_type(4)));
typedef unsigned short us8v __attribute__((ext_vector_type(8)));

// ---------------- stage-1 core: trimmed-mean aggregation ---------------------
// CRITICAL invariants (measured):
//  * node index must be wave-uniform scalar — per-lane i => ~10x VALU blowup.
//  * gather MUST stay the per-N specialized unconditional unroll. R6's
//    wave-uniform-predicated gather + reg rotate => 5x VALU (46->150us).
//  * private arrays pow2-sized, static indices (else LDS-promote + spill).
//  * R3 lesson: NO cross-block spin/fence protocols (container hang).
//  * R5 lesson: gather is LATENCY-bound, not BW-bound (fp16 gather halved
//    FETCH yet ran +5us slower, absmax 4.5x worse). fp32 gather restored.
//  * R7: ko[] (original-order copy, read only AFTER the sort) moves to a
//    private per-thread LDS column — peak regs during sort drop 64->32,
//    lifting occupancy ~3->4 waves/SIMD for latency hiding. Layout [d][tid]:
//    fixed d => consecutive lanes, consecutive banks (2 lanes/bank, free).

template <int SZ, int NV>
__device__ __forceinline__ void oe_sort_n(float (&a)[SZ]) {
#pragma unroll
  for (int p = 1; p < SZ; p <<= 1) {
#pragma unroll
    for (int q = p; q >= 1; q >>= 1) {
#pragma unroll
      for (int j = q % p; j <= SZ - 1 - q; j += 2 * q) {
#pragma unroll
        for (int i = 0; i < q; ++i) {
          int x = i + j, y = i + j + q;
          if (y < NV && (x / (2 * p)) == (y / (2 * p))) {  // y<NV ⊆ y<SZ
            float mn = fminf(a[x], a[y]);
            float mx = fmaxf(a[x], a[y]);
            a[x] = mn;
            a[y] = mx;
          }
        }
      }
    }
  }
}

// b = max(min(n/2 - (1-n%2), (int)floor_f32(n*0.45f)), 1) — f32 mult matches
// jnp exactly (e.g. n=20: 20*0.449999988f = 8.9999998 -> 8, not 9).
template <int N>
struct TrimB {
  static constexpr int b_raw = N / 2 - (1 - (N & 1));
  static constexpr int b_cap = (int)((float)N * 0.45f);  // trunc == floor (pos)
  static constexpr int b_min = b_raw < b_cap ? b_raw : b_cap;
  static constexpr int value = b_min > 1 ? b_min : 1;
};

// Exact trimmed sum, exact-n specialization. Stable-rank semantics match
// jnp.argsort (ties by slot). Fast path: no equal-key run straddles either
// trim boundary -> pure value test. Slow path (rare): exact stable-rank scan.
// kbuf: per-thread LDS column (stride 256 floats) holding the original-order
// gathered values; k[] (registers) is sorted in place.
template <int SZ, int N>
__device__ __forceinline__ float trimmed_sum_n(const float* __restrict__ h,
                                               const float* __restrict__ norm,
                                               const int* __restrict__ nbr_row,
                                               int f, float* kbuf) {
  constexpr int B = TrimB<N>::value;
  constexpr int NB = N - B;

  float nrm[SZ];  // wave-uniform -> SGPRs
  float k[SZ];
#pragma unroll
  for (int d = 0; d < N; ++d) {
    int src = nbr_row[d];       // scalar load
    nrm[d] = norm[src];         // scalar load
    float v = h[src * F + f];   // vector load, coalesced 256B/wave
    kbuf[d * 256] = v;          // ds_write: original order to LDS
    k[d] = v;
  }
#pragma unroll
  for (int d = N; d < SZ; ++d) k[d] = FLT_MAX;  // pads sort past all valid keys

  oe_sort_n<SZ, N>(k);

  const float lo  = k[B];       // compile-time positions -> direct reg reads
  const float hi  = k[NB - 1];
  const float lom = k[B - 1];
  const float him = k[NB];

  float sum = 0.f;
  if ((lom < lo) & (hi < him)) {
#pragma unroll
    for (int d = 0; d < N; ++d) {
      const float v = kbuf[d * 256];  // ds_read, conflict-free, pipelined
      bool keep = (v >= lo) & (v <= hi);
      sum = fmaf(keep ? v : 0.f, nrm[d], sum);
    }
  } else {
    int c_lt_lo = 0, c_lt_hi = 0;
#pragma unroll
    for (int d = 0; d < N; ++d) {
      const float v = kbuf[d * 256];
      c_lt_lo += (v < lo) ? 1 : 0;
      c_lt_hi += (v < hi) ? 1 : 0;
    }
    int run_lo = 0, run_hi = 0;
#pragma unroll
    for (int d = 0; d < N; ++d) {
      const float kd = kbuf[d * 256];
      const float m = kd * nrm[d];
      const bool eql = (kd == lo);
      const bool eqh = (kd == hi);
      const bool lh = (lo < hi);
      const bool btw = (kd > lo) & (kd < hi);
      const int r_lo = c_lt_lo + run_lo;  // stable rank if kd==lo
      const int r_hi = c_lt_hi + run_hi;  // stable rank if kd==hi
      const bool inc = btw
                     | (eql & (r_lo >= B) & (lh | (r_lo < NB)))
                     | (lh & eqh & (r_hi < NB));
      sum += inc ? m : 0.f;
      run_lo += eql ? 1 : 0;
      run_hi += eqh ? 1 : 0;
    }
  }
  return sum;
}

// a = hi + lo captures ~22 mantissa bits; packed into one u32 (hi low16).
__device__ __forceinline__ unsigned int split_pack(float v) {
  _Float16 hi = (_Float16)v;            // rne f32->f16
  _Float16 lo = (_Float16)(v - (float)hi);
  unsigned short hb = __builtin_bit_cast(unsigned short, hi);
  unsigned short lb = __builtin_bit_cast(unsigned short, lo);
  return (unsigned int)hb | ((unsigned int)lb << 16);
}

// ---------------- W pre-split: fp32 [k][n] -> fp16 hi/lo transposed [n][k] ---
__global__ __launch_bounds__(256) void whl_prep(const float* __restrict__ W,
                                                _Float16* __restrict__ Whl) {
  const int e = blockIdx.x * 256 + threadIdx.x;  // e = n*128 + k
  const int n = e >> 7, k = e & 127;
  const float w = W[k * F + n];
  const _Float16 hi = (_Float16)w;
  Whl[e] = hi;
  Whl[16384 + e] = (_Float16)(w - (float)hi);
}

// ---------------- fused kernel: 16-node aggregation + own GEMM tile ----------
// Phase 1: 8 iterations x 2 nodes (each 128-thread half = one node; i is SGPR;
// R4-verified structure). Rows land in LDS As[16][128] packed u32, XOR-
// swizzled (idx ^ ((row&7)<<2)).
// Phase 2 (after ONE barrier): 16x128 fp16x2-split MFMA tile (refcheck-
// verified operand/D layouts), B from global Whl (64KB, L2-hot).
__global__ __launch_bounds__(256) void gcn_fused(
    const float* __restrict__ h, const float* __restrict__ norm,
    const int* __restrict__ nbr, const int* __restrict__ deg,
    const _Float16* __restrict__ Whl, const float* __restrict__ bias,
    float* __restrict__ out) {
  __shared__ float ko_lds[32 * 256];      // 32 KB: [d][tid] original-order vals
  __shared__ unsigned int As[MTILE * F];  // 8 KB, swizzled split-packed rows
  const int tid = threadIdx.x;
  const int hw = __builtin_amdgcn_readfirstlane(tid) >> 7;  // 0/1, SGPR
  const int f = tid & 127;
  const int base = blockIdx.x * MTILE;
  float* kbuf = ko_lds + tid;             // private column, stride 256

  // ---------------- phase 1: aggregation for this block's 16 nodes ----------
#pragma unroll 1  // keep ONE copy of the giant switch (I$)
  for (int it = 0; it < 8; ++it) {
    const int nl = it * 2 + hw;                 // node-local 0..15, SGPR
    const int i = base + nl;                    // global node, SGPR
    const int n = deg[i];
    const float ni = norm[i];
    const float hif = h[i * F + f];

    float val;
    if (n <= 3) {  // N_NEIGH_THRESHOLD branch (exact)
      val = (float)n * hif * ni * ni;
    } else {
      const int* nbr_row = nbr + i * MAXD;
      float ts;
      int b;
      switch (n) {
#define TS_CASE(NN, SS) \
        case NN: ts = trimmed_sum_n<SS, NN>(h, norm, nbr_row, f, kbuf); b = TrimB<NN>::value; break;
        TS_CASE(4, 4)
        TS_CASE(5, 8) TS_CASE(6, 8) TS_CASE(7, 8) TS_CASE(8, 8)
        TS_CASE(9, 16) TS_CASE(10, 16) TS_CASE(11, 16) TS_CASE(12, 16)
        TS_CASE(13, 16) TS_CASE(14, 16) TS_CASE(15, 16) TS_CASE(16, 16)
        TS_CASE(17, 32) TS_CASE(18, 32) TS_CASE(19, 32) TS_CASE(20, 32)
        TS_CASE(21, 32) TS_CASE(22, 32) TS_CASE(23, 32) TS_CASE(24, 32)
        TS_CASE(25, 32) TS_CASE(26, 32) TS_CASE(27, 32) TS_CASE(28, 32)
        TS_CASE(29, 32) TS_CASE(30, 32) TS_CASE(31, 32)
        default: ts = trimmed_sum_n<32, 32>(h, norm, nbr_row, f, kbuf); b = TrimB<32>::value; break;
#undef TS_CASE
      }
      val = (ts + hif * ni * (float)(2 * b)) * ni;
    }
    // swizzled LDS write: conflict-free (XOR const per node-row)
    As[nl * F + (f ^ ((nl & 7) << 2))] = split_pack(val);
  }

  __syncthreads();  // the only barrier: As tile complete

  // ---------------- phase 2: 16x128 fp16x2-split MFMA tile ------------------
  const int lane = tid & 63;
  const int wv = tid >> 6;      // wave -> cols [wv*32, wv*32+32)
  const int l16 = lane & 15;    // A row / B col within fragment
  const int kg = lane >> 4;     // k-group 0..3 (8 k each)
  const int row0 = base;
  const int colb = wv * 32;
  const int s = (l16 & 7) << 2; // read-side un-swizzle for row=l16

  f32x4 acc[2];
  acc[0] = (f32x4){0.f, 0.f, 0.f, 0.f};
  acc[1] = (f32x4){0.f, 0.f, 0.f, 0.f};

#pragma unroll
  for (int kc = 0; kc < F; kc += 32) {
    const int k0 = kc + kg * 8;
    // A fragment: rows l16, k = k0..k0+7. Two b128 reads; swizzle maps each
    // 4-aligned group bijectively, retrieving f = k0..k0+7 in order.
    u32x4 p0 = *(const u32x4*)(As + l16 * F + ((k0 + 0) ^ s));
    u32x4 p1 = *(const u32x4*)(As + l16 * F + ((k0 + 4) ^ s));
    us8v s0 = __builtin_bit_cast(us8v, p0);  // {h0,l0,h1,l1,...}
    us8v s1 = __builtin_bit_cast(us8v, p1);
    half8 ah = __builtin_bit_cast(half8,
        (us8v)__builtin_shufflevector(s0, s1, 0, 2, 4, 6, 8, 10, 12, 14));
    half8 al = __builtin_bit_cast(half8,
        (us8v)__builtin_shufflevector(s0, s1, 1, 3, 5, 7, 9, 11, 13, 15));
#pragma unroll
    for (int cf = 0; cf < 2; ++cf) {
      const int n = colb + cf * 16 + l16;
      half8 bh = *(const half8*)(Whl + n * F + k0);
      half8 bl = *(const half8*)(Whl + 16384 + n * F + k0);
      acc[cf] = __builtin_amdgcn_mfma_f32_16x16x32_f16(ah, bh, acc[cf], 0, 0, 0);
      acc[cf] = __builtin_amdgcn_mfma_f32_16x16x32_f16(ah, bl, acc[cf], 0, 0, 0);
      acc[cf] = __builtin_amdgcn_mfma_f32_16x16x32_f16(al, bh, acc[cf], 0, 0, 0);
    }
  }

  // bias + relu. D mapping: col = l16 (+cf*16+colb), row = kg*4 + r
  // (verified C/D layout, m89 + R1/R2/R4 refcheck).
#pragma unroll
  for (int cf = 0; cf < 2; ++cf) {
    const int col = colb + cf * 16 + l16;
    const float bv = bias[col];
#pragma unroll
    for (int r = 0; r < 4; ++r) {
      const int row = row0 + kg * 4 + r;
      out[(size_t)row * F + col] = fmaxf(acc[cf][r] + bv, 0.f);
    }
  }
}

extern "C" void kernel_launch(void* const* d_in, const int* in_sizes, int n_in,
                              void* d_out, int out_size, void* d_ws, size_t ws_size,
                              hipStream_t stream) {
  const float* h = (const float*)d_in[0];
  const float* norm = (const float*)d_in[1];
  const float* weight = (const float*)d_in[2];
  const float* bias = (const float*)d_in[3];
  const int* nbr = (const int*)d_in[4];
  const int* deg = (const int*)d_in[5];
  float* out = (float*)d_out;

  _Float16* Whl = (_Float16*)d_ws;  // 64 KB: split W^T hi|lo

  whl_prep<<<64, 256, 0, stream>>>(weight, Whl);
  gcn_fused<<<NBLK, 256, 0, stream>>>(h, norm, nbr, deg, Whl, bias, out);
}

// Round 8
// 113.146 us; speedup vs baseline: 1.8831x; 1.0827x over previous
//
#include <hip/hip_runtime.h>
#include <hip/hip_fp16.h>
#include <cfloat>
#include <cmath>

#define N_NODES 20000
#define MAXD 32
#define F 128

// stage-2 MFMA tiling: 20000 = 625 * 32 exactly -> no remainder, no guards
#define MTILE 32
#define NBLK (N_NODES / MTILE)  // 625 blocks

typedef _Float16 half8 __attribute__((ext_vector_type(8)));
typedef float f32x4 __attribute__((ext_vector_type(4)));
typedef unsigned int u32x4 __attribute__((ext_vector_type(4)));
typedef unsigned short us8v __attribute__((ext_vector_type(8)));

// ---------------- stage 1: trimmed-mean aggregation (R11 core) ---------------
// CRITICAL invariants (measured across this + prior session):
//  * node index must be blockIdx-derived (scalar) — threadIdx-derived i =>
//    ~10x VALU blowup (415us).
//  * gather MUST stay the per-N specialized unconditional unroll. R6's
//    wave-uniform-predicated gather + reg rotate => 5x VALU (46->150us).
//  * private arrays pow2-sized with static indices — else LDS-promote+spill.
//  * 1 node / 128-thread block: best load balance (beats 16-node fused
//    blocks, R4: aggregation ~44us vs 38us here).
//  * R5: gather is LATENCY-bound, not BW-bound (fp16 gather halved FETCH
//    61.7->30.4MB yet +5us slower, absmax 4.5x worse). fp32 gather final.
//  * R7: ko[] -> LDS cut regs but LDS became the occupancy limiter (-9us).
//  * Store: ONE packed u32/lane (fp16 hi|lo<<16) — same coalescing as f32.
//  * Near the random-gather memory floor (~169 MB scattered 512B segments
//    at ~4.4 TB/s effective L2/L3).

template <int SZ, int NV>
__device__ __forceinline__ void oe_sort_n(float (&a)[SZ]) {
#pragma unroll
  for (int p = 1; p < SZ; p <<= 1) {
#pragma unroll
    for (int q = p; q >= 1; q >>= 1) {
#pragma unroll
      for (int j = q % p; j <= SZ - 1 - q; j += 2 * q) {
#pragma unroll
        for (int i = 0; i < q; ++i) {
          int x = i + j, y = i + j + q;
          if (y < NV && (x / (2 * p)) == (y / (2 * p))) {  // y<NV ⊆ y<SZ
            float mn = fminf(a[x], a[y]);
            float mx = fmaxf(a[x], a[y]);
            a[x] = mn;
            a[y] = mx;
          }
        }
      }
    }
  }
}

// b = max(min(n/2 - (1-n%2), (int)floor_f32(n*0.45f)), 1) — f32 mult matches
// jnp exactly (e.g. n=20: 20*0.449999988f = 8.9999998 -> 8, not 9).
template <int N>
struct TrimB {
  static constexpr int b_raw = N / 2 - (1 - (N & 1));
  static constexpr int b_cap = (int)((float)N * 0.45f);  // trunc == floor (pos)
  static constexpr int b_min = b_raw < b_cap ? b_raw : b_cap;
  static constexpr int value = b_min > 1 ? b_min : 1;
};

// Exact trimmed sum, exact-n specialization. Stable-rank semantics match
// jnp.argsort (ties by slot). Fast path: no equal-key run straddles either
// trim boundary -> pure value test. Slow path (rare): exact stable-rank scan.
template <int SZ, int N>
__device__ __forceinline__ float trimmed_sum_n(const float* __restrict__ h,
                                               const float* __restrict__ norm,
                                               const int* __restrict__ nbr_row,
                                               int f) {
  constexpr int B = TrimB<N>::value;
  constexpr int NB = N - B;

  float ko[SZ];
  float nrm[SZ];  // block-uniform -> SGPRs
  float k[SZ];
#pragma unroll
  for (int d = 0; d < N; ++d) {
    int src = nbr_row[d];       // scalar load
    nrm[d] = norm[src];         // scalar load
    ko[d] = h[src * F + f];     // vector load, coalesced 256B/wave
    k[d] = ko[d];
  }
#pragma unroll
  for (int d = N; d < SZ; ++d) k[d] = FLT_MAX;  // pads sort past all valid keys

  oe_sort_n<SZ, N>(k);

  const float lo  = k[B];       // compile-time positions -> direct reg reads
  const float hi  = k[NB - 1];
  const float lom = k[B - 1];
  const float him = k[NB];

  float sum = 0.f;
  if ((lom < lo) & (hi < him)) {
#pragma unroll
    for (int d = 0; d < N; ++d) {
      bool keep = (ko[d] >= lo) & (ko[d] <= hi);
      sum = fmaf(keep ? ko[d] : 0.f, nrm[d], sum);
    }
  } else {
    int c_lt_lo = 0, c_lt_hi = 0;
#pragma unroll
    for (int d = 0; d < N; ++d) {
      c_lt_lo += (ko[d] < lo) ? 1 : 0;
      c_lt_hi += (ko[d] < hi) ? 1 : 0;
    }
    int run_lo = 0, run_hi = 0;
#pragma unroll
    for (int d = 0; d < N; ++d) {
      const float kd = ko[d];
      const float m = kd * nrm[d];
      const bool eql = (kd == lo);
      const bool eqh = (kd == hi);
      const bool lh = (lo < hi);
      const bool btw = (kd > lo) & (kd < hi);
      const int r_lo = c_lt_lo + run_lo;  // stable rank if kd==lo
      const int r_hi = c_lt_hi + run_hi;  // stable rank if kd==hi
      const bool inc = btw
                     | (eql & (r_lo >= B) & (lh | (r_lo < NB)))
                     | (lh & eqh & (r_hi < NB));
      sum += inc ? m : 0.f;
      run_lo += eql ? 1 : 0;
      run_hi += eqh ? 1 : 0;
    }
  }
  return sum;
}

// a = hi + lo captures ~22 mantissa bits; packed into one u32 (hi low16).
__device__ __forceinline__ unsigned int split_pack(float v) {
  _Float16 hi = (_Float16)v;            // rne f32->f16
  _Float16 lo = (_Float16)(v - (float)hi);
  unsigned short hb = __builtin_bit_cast(unsigned short, hi);
  unsigned short lb = __builtin_bit_cast(unsigned short, lo);
  return (unsigned int)hb | ((unsigned int)lb << 16);
}

__global__ __launch_bounds__(128) void gcn_stage1(const float* __restrict__ h,
                                                  const float* __restrict__ norm,
                                                  const int* __restrict__ nbr,
                                                  const int* __restrict__ deg,
                                                  const float* __restrict__ W,
                                                  unsigned int* __restrict__ Ap,
                                                  _Float16* __restrict__ Whl) {
  const int i = blockIdx.x;       // MUST stay blockIdx-derived (scalar)
  const int f = threadIdx.x;

  // blocks 0..15: also pre-split + transpose W into workspace for stage 2.
  // Whl[0][n][k] = hi, Whl[16384 + n*F + k] = lo. 2048 x 2B stores/block.
  if (i < 16) {
    const int e0 = (i * 128 + f) * 8;
#pragma unroll
    for (int j = 0; j < 8; ++j) {
      const int e = e0 + j;
      const int k = e >> 7, n = e & 127;
      const float w = W[e];
      const _Float16 whi = (_Float16)w;
      Whl[n * F + k] = whi;
      Whl[16384 + n * F + k] = (_Float16)(w - (float)whi);
    }
  }

  const int n = deg[i];           // scalar
  const float ni = norm[i];
  const float hif = h[i * F + f];
  const int idx = i * F + f;

  if (n <= 3) {  // N_NEIGH_THRESHOLD branch
    Ap[idx] = split_pack((float)n * hif * ni * ni);
    return;
  }

  const int* nbr_row = nbr + i * MAXD;
  float ts;
  int b;
  switch (n) {  // scalar switch; each case fully compile-time specialized
#define TS_CASE(NN, SS) \
    case NN: ts = trimmed_sum_n<SS, NN>(h, norm, nbr_row, f); b = TrimB<NN>::value; break;
    TS_CASE(4, 4)
    TS_CASE(5, 8) TS_CASE(6, 8) TS_CASE(7, 8) TS_CASE(8, 8)
    TS_CASE(9, 16) TS_CASE(10, 16) TS_CASE(11, 16) TS_CASE(12, 16)
    TS_CASE(13, 16) TS_CASE(14, 16) TS_CASE(15, 16) TS_CASE(16, 16)
    TS_CASE(17, 32) TS_CASE(18, 32) TS_CASE(19, 32) TS_CASE(20, 32)
    TS_CASE(21, 32) TS_CASE(22, 32) TS_CASE(23, 32) TS_CASE(24, 32)
    TS_CASE(25, 32) TS_CASE(26, 32) TS_CASE(27, 32) TS_CASE(28, 32)
    TS_CASE(29, 32) TS_CASE(30, 32) TS_CASE(31, 32)
    default: ts = trimmed_sum_n<32, 32>(h, norm, nbr_row, f); b = TrimB<32>::value; break;
#undef TS_CASE
  }

  Ap[idx] = split_pack((ts + hif * ni * (float)(2 * b)) * ni);
}

// ---------------- stage 2: out = relu(accum @ W + bias), fp16x2-split MFMA ----
// fp32 SGEMM sat at ~18us = 36 TF = 23% of the 157 TF vector-fp32 peak — CDNA4
// has no fp32 MFMA, so run a=(ah+al), w=(wh+wl) on the f16 MFMA pipe with the
// 3 dominant products ah*wh + ah*wl + al*wh (al*wl ~ 2^-22 rel, dropped).
// Refcheck-validated (absmax 0.0078). Structure:
//  * NO LDS, NO barriers, NO per-block W conversion: W pre-split by stage 1
//    into a 64KB global buffer (hot in every XCD L2 after first touch).
//  * A fragments load packed u32 straight from global (L2/L3-resident),
//    deinterleaved with 2 shufflevectors (v_perm_b32, VALU pipe ∥ MFMA pipe).
//    Operand mapping (lane&15 = row/col, lane>>4 = k-group of 8) is the
//    refcheck-verified gfx950 16x16x32 layout.
//  * MTILE=32 -> 625 blocks (exact: 20000=625*32, no guards), ~2.4 blocks/CU.
//  * Per wave (32 cols x 32 rows): 2rf x 2cf x 4kc x 3 = 48 MFMA; pure-MFMA
//    time ~0.25us total — kernel is latency/BW, floor ~4-5us.
__global__ __launch_bounds__(256) void gcn_gemm_mfma(
    const unsigned int* __restrict__ Ap, const _Float16* __restrict__ Whl,
    const float* __restrict__ bias, float* __restrict__ out) {
  const int t = threadIdx.x;
  const int lane = t & 63;
  const int wv = t >> 6;        // wave id -> cols [wv*32, wv*32+32)
  const int l16 = lane & 15;
  const int kg = lane >> 4;     // k-group 0..3 (8 k each)
  const int row0 = blockIdx.x * MTILE;
  const int colb = wv * 32;

  f32x4 acc[2][2];
#pragma unroll
  for (int rf = 0; rf < 2; ++rf)
#pragma unroll
    for (int cf = 0; cf < 2; ++cf) acc[rf][cf] = (f32x4){0.f, 0.f, 0.f, 0.f};

#pragma unroll
  for (int kc = 0; kc < F; kc += 32) {
    half8 ah[2], al[2], bh[2], bl[2];
#pragma unroll
    for (int rf = 0; rf < 2; ++rf) {
      const int row = row0 + rf * 16 + l16;
      const unsigned int* p = Ap + (size_t)row * F + kc + kg * 8;
      u32x4 p0 = *(const u32x4*)p;        // 2x dwordx4, 16B aligned
      u32x4 p1 = *(const u32x4*)(p + 4);
      us8v s0 = __builtin_bit_cast(us8v, p0);  // {h0,l0,h1,l1,...}
      us8v s1 = __builtin_bit_cast(us8v, p1);
      ah[rf] = __builtin_bit_cast(half8,
          (us8v)__builtin_shufflevector(s0, s1, 0, 2, 4, 6, 8, 10, 12, 14));
      al[rf] = __builtin_bit_cast(half8,
          (us8v)__builtin_shufflevector(s0, s1, 1, 3, 5, 7, 9, 11, 13, 15));
    }
#pragma unroll
    for (int cf = 0; cf < 2; ++cf) {
      const int n = colb + cf * 16 + l16;
      bh[cf] = *(const half8*)(Whl + n * F + kc + kg * 8);
      bl[cf] = *(const half8*)(Whl + 16384 + n * F + kc + kg * 8);
    }
#pragma unroll
    for (int rf = 0; rf < 2; ++rf)
#pragma unroll
      for (int cf = 0; cf < 2; ++cf) {
        acc[rf][cf] = __builtin_amdgcn_mfma_f32_16x16x32_f16(ah[rf], bh[cf], acc[rf][cf], 0, 0, 0);
        acc[rf][cf] = __builtin_amdgcn_mfma_f32_16x16x32_f16(ah[rf], bl[cf], acc[rf][cf], 0, 0, 0);
        acc[rf][cf] = __builtin_amdgcn_mfma_f32_16x16x32_f16(al[rf], bh[cf], acc[rf][cf], 0, 0, 0);
      }
  }

  // epilogue: bias + relu. D mapping: col = lane&15 (+cf*16+colb),
  // row = rf*16 + (lane>>4)*4 + r  (verified C/D layout, m89 + refcheck).
#pragma unroll
  for (int cf = 0; cf < 2; ++cf) {
    const int col = colb + cf * 16 + l16;
    const float bv = bias[col];
#pragma unroll
    for (int rf = 0; rf < 2; ++rf) {
#pragma unroll
      for (int r = 0; r < 4; ++r) {
        const int row = row0 + rf * 16 + kg * 4 + r;
        out[(size_t)row * F + col] = fmaxf(acc[rf][cf][r] + bv, 0.f);
      }
    }
  }
}

extern "C" void kernel_launch(void* const* d_in, const int* in_sizes, int n_in,
                              void* d_out, int out_size, void* d_ws, size_t ws_size,
                              hipStream_t stream) {
  const float* h = (const float*)d_in[0];
  const float* norm = (const float*)d_in[1];
  const float* weight = (const float*)d_in[2];
  const float* bias = (const float*)d_in[3];
  const int* nbr = (const int*)d_in[4];
  const int* deg = (const int*)d_in[5];
  float* out = (float*)d_out;

  unsigned int* Ap = (unsigned int*)d_ws;             // 20000*128*4 = 10.24 MB
  _Float16* Whl = (_Float16*)(Ap + (size_t)N_NODES * F);  // 64 KB hi+lo split W

  gcn_stage1<<<N_NODES, 128, 0, stream>>>(h, norm, nbr, deg, weight, Ap, Whl);
  gcn_gemm_mfma<<<NBLK, 256, 0, stream>>>(Ap, Whl, bias, out);
}